// Round 3
// baseline (138.510 us; speedup 1.0000x reference)
//
#include <hip/hip_runtime.h>

#define NPIX    76800      // 240*320
#define WIDTH   320
#define HEIGHT  240
#define NS      9
#define NTOT    (NPIX*NS)  // 691200
#define VDIM    320

// tiling: 8x8 pixel tiles, 576 threads/block (9 waves), 40x30 = 1200 tiles
#define TILE    8
#define TILES_X 40
#define TILES_Y 30
#define NTILES  1200
#define NXCD    8
#define TILES_PER_XCD (NTILES / NXCD)   // 150, exact

// output offsets (all float32 elements, concatenated in return order)
#define OFF_FV  0
#define OFF_FW  691200
#define OFF_RP  1382400
#define OFF_D   3456000
#define OFF_I   3532800
#define OFF_W8  20121600
#define OFF_C   25651200

typedef float f32x4 __attribute__((ext_vector_type(4)));

__global__ __launch_bounds__(576) void extractor_kernel(
    const float* __restrict__ depth,
    const float* __restrict__ extr,      // 4x4 row-major
    const float* __restrict__ intr,      // 3x3 row-major
    const float* __restrict__ vol,       // 320^3
    const float* __restrict__ wvol,      // 320^3
    const float* __restrict__ origin,    // 3
    const float* __restrict__ resolution,// 1
    float* __restrict__ out)
{
    // ---- XCD-chunked bijective block swizzle (1200 % 8 == 0) ----
    const int bid     = blockIdx.x;
    const int tileIdx = (bid & (NXCD - 1)) * TILES_PER_XCD + (bid >> 3);
    const int tile_row = tileIdx / TILES_X;
    const int tile_col = tileIdx - tile_row * TILES_X;

    const int t  = threadIdx.x;          // 0..575
    const int lp = t / 9;                // local pixel 0..63
    const int s  = t - lp * 9;           // sample 0..8
    const int tx = lp & (TILE - 1);
    const int ty = lp >> 3;

    const int row = tile_row * TILE + ty;   // v
    const int col = tile_col * TILE + tx;   // u
    const int p   = row * WIDTH + col;
    const int tid = p * NS + s;             // global (pixel,sample) output index

    const float z = depth[p];

    // --- 3x3 inverse of intrinsics (adjugate; uniform -> scalar ops) ---
    const float a00=intr[0], a01=intr[1], a02=intr[2];
    const float a10=intr[3], a11=intr[4], a12=intr[5];
    const float a20=intr[6], a21=intr[7], a22=intr[8];
    const float det = a00*(a11*a22 - a12*a21)
                    - a01*(a10*a22 - a12*a20)
                    + a02*(a10*a21 - a11*a20);
    const float id = 1.0f / det;
    const float i00 = (a11*a22 - a12*a21)*id;
    const float i01 = (a02*a21 - a01*a22)*id;
    const float i02 = (a01*a12 - a02*a11)*id;
    const float i10 = (a12*a20 - a10*a22)*id;
    const float i11 = (a00*a22 - a02*a20)*id;
    const float i12 = (a02*a10 - a00*a12)*id;
    const float i20 = (a10*a21 - a11*a20)*id;
    const float i21 = (a01*a20 - a00*a21)*id;
    const float i22 = (a00*a11 - a01*a10)*id;

    // pts_p = (u*z, v*z, z)
    const float up = (float)col * z;
    const float vp = (float)row * z;
    const float pcx = i00*up + i01*vp + i02*z;
    const float pcy = i10*up + i11*vp + i12*z;
    const float pcz = i20*up + i21*vp + i22*z;

    // world coords = (E @ [pc,1])[:3]
    const float cwx = extr[0]*pcx + extr[1]*pcy + extr[2]*pcz  + extr[3];
    const float cwy = extr[4]*pcx + extr[5]*pcy + extr[6]*pcz  + extr[7];
    const float cwz = extr[8]*pcx + extr[9]*pcy + extr[10]*pcz + extr[11];

    const float ox = origin[0], oy = origin[1], oz = origin[2];
    const float res = resolution[0];

    // voxel coords
    const float cvx = (cwx - ox) / res;
    const float cvy = (cwy - oy) / res;
    const float cvz = (cwz - oz) / res;
    const float evx = (extr[3]  - ox) / res;
    const float evy = (extr[7]  - oy) / res;
    const float evz = (extr[11] - oz) / res;

    float dx = cvx - evx, dy = cvy - evy, dz = cvz - evz;
    const float nrm = sqrtf(dx*dx + dy*dy + dz*dz);
    const float dn  = fmaxf(nrm, 1e-12f);
    dx /= dn; dy /= dn; dz /= dn;

    const float offs = (float)(s - 4);   // offs in [-4,4]
    const float pt[3] = { cvx + offs*dx, cvy + offs*dy, cvz + offs*dz };

    // --- trilinear setup ---
    float alpha[3], nb[3], fidx[3];
    #pragma unroll
    for (int k = 0; k < 3; ++k) {
        const float f  = floorf(pt[k]);
        const float c  = f + 0.5f;
        const float df = c - pt[k];
        nb[k]    = (df > 0.0f) ? 1.0f : ((df < 0.0f) ? -1.0f : 0.0f);
        alpha[k] = fabsf(pt[k] - c);
        fidx[k]  = f;
    }

    float fv = 0.0f, fw = 0.0f;
    float indsbuf[24];
    float w8buf[8];

    #pragma unroll
    for (int c = 0; c < 8; ++c) {
        float wgt = 1.0f;
        bool valid = true;
        int ii[3];
        #pragma unroll
        for (int k = 0; k < 3; ++k) {
            const float bit = ((c >> (2 - k)) & 1) ? 1.0f : 0.0f;
            wgt *= (bit > 0.0f) ? alpha[k] : (1.0f - alpha[k]);
            const float fi = fidx[k] + bit * nb[k];
            valid = valid && (fi >= 0.0f) && (fi < (float)VDIM);
            const float fc = fminf(fmaxf(fi, 0.0f), (float)(VDIM - 1));
            ii[k] = (int)fc;
            indsbuf[c*3 + k] = (float)ii[k];
        }
        const int lin = (ii[0]*VDIM + ii[1])*VDIM + ii[2];
        const float v  = vol[lin];
        const float wv = wvol[lin];
        if (valid) { fv += v * wgt; fw += wv * wgt; }
        w8buf[c] = wgt;
    }

    // --- streaming writes (non-temporal: don't pollute L2, gathers need it) ---
    __builtin_nontemporal_store(fv, out + OFF_FV + tid);
    __builtin_nontemporal_store(fw, out + OFF_FW + tid);
    __builtin_nontemporal_store(pt[0], out + OFF_RP + tid*3 + 0);
    __builtin_nontemporal_store(pt[1], out + OFF_RP + tid*3 + 1);
    __builtin_nontemporal_store(pt[2], out + OFF_RP + tid*3 + 2);

    f32x4* ip = reinterpret_cast<f32x4*>(out + OFF_I + tid*24);
    #pragma unroll
    for (int q = 0; q < 6; ++q) {
        f32x4 v4 = { indsbuf[q*4+0], indsbuf[q*4+1], indsbuf[q*4+2], indsbuf[q*4+3] };
        __builtin_nontemporal_store(v4, ip + q);
    }

    f32x4* wp = reinterpret_cast<f32x4*>(out + OFF_W8 + tid*8);
    f32x4 w0 = { w8buf[0], w8buf[1], w8buf[2], w8buf[3] };
    f32x4 w1 = { w8buf[4], w8buf[5], w8buf[6], w8buf[7] };
    __builtin_nontemporal_store(w0, wp + 0);
    __builtin_nontemporal_store(w1, wp + 1);

    if (s == 0) {
        __builtin_nontemporal_store(z, out + OFF_D + p);
        __builtin_nontemporal_store(cwx, out + OFF_C + p*3 + 0);
        __builtin_nontemporal_store(cwy, out + OFF_C + p*3 + 1);
        __builtin_nontemporal_store(cwz, out + OFF_C + p*3 + 2);
    }
}

extern "C" void kernel_launch(void* const* d_in, const int* in_sizes, int n_in,
                              void* d_out, int out_size, void* d_ws, size_t ws_size,
                              hipStream_t stream) {
    const float* depth      = (const float*)d_in[0];
    const float* extr       = (const float*)d_in[1];
    const float* intr       = (const float*)d_in[2];
    const float* vol        = (const float*)d_in[3];
    const float* wvol       = (const float*)d_in[4];
    const float* origin     = (const float*)d_in[5];
    const float* resolution = (const float*)d_in[6];
    float* out = (float*)d_out;

    extractor_kernel<<<NTILES, TILE*TILE*NS, 0, stream>>>(
        depth, extr, intr, vol, wvol, origin, resolution, out);
}

// Round 4
// 71.140 us; speedup vs baseline: 1.9470x; 1.9470x over previous
//
#include <hip/hip_runtime.h>

#define NPIX    76800      // 240*320
#define WIDTH   320
#define HEIGHT  240
#define NS      9
#define NTOT    (NPIX*NS)  // 691200
#define VDIM    320

// tiling: 8x8 pixel tiles, 576 threads/block (9 waves), 40x30 = 1200 tiles
#define TILE    8
#define TILES_X 40
#define TILES_Y 30
#define NTILES  1200
#define NXCD    8
#define TILES_PER_XCD (NTILES / NXCD)   // 150, exact

// output offsets (all float32 elements, concatenated in return order)
#define OFF_FV  0
#define OFF_FW  691200
#define OFF_RP  1382400
#define OFF_D   3456000
#define OFF_I   3532800
#define OFF_W8  20121600
#define OFF_C   25651200

typedef float f32x4 __attribute__((ext_vector_type(4)));

__global__ __launch_bounds__(576) void extractor_kernel(
    const float* __restrict__ depth,
    const float* __restrict__ extr,      // 4x4 row-major
    const float* __restrict__ intr,      // 3x3 row-major
    const float* __restrict__ vol,       // 320^3
    const float* __restrict__ wvol,      // 320^3
    const float* __restrict__ origin,    // 3
    const float* __restrict__ resolution,// 1
    float* __restrict__ out)
{
    // ---- XCD-chunked bijective block swizzle (1200 % 8 == 0) ----
    const int bid     = blockIdx.x;
    const int tileIdx = (bid & (NXCD - 1)) * TILES_PER_XCD + (bid >> 3);
    const int tile_row = tileIdx / TILES_X;
    const int tile_col = tileIdx - tile_row * TILES_X;

    const int t  = threadIdx.x;          // 0..575
    const int lp = t / 9;                // local pixel 0..63
    const int s  = t - lp * 9;           // sample 0..8
    const int tx = lp & (TILE - 1);
    const int ty = lp >> 3;

    const int row = tile_row * TILE + ty;   // v
    const int col = tile_col * TILE + tx;   // u
    const int p   = row * WIDTH + col;
    const int tid = p * NS + s;             // global (pixel,sample) output index

    const float z = depth[p];

    // --- 3x3 inverse of intrinsics (adjugate; uniform -> scalar ops) ---
    const float a00=intr[0], a01=intr[1], a02=intr[2];
    const float a10=intr[3], a11=intr[4], a12=intr[5];
    const float a20=intr[6], a21=intr[7], a22=intr[8];
    const float det = a00*(a11*a22 - a12*a21)
                    - a01*(a10*a22 - a12*a20)
                    + a02*(a10*a21 - a11*a20);
    const float id = 1.0f / det;
    const float i00 = (a11*a22 - a12*a21)*id;
    const float i01 = (a02*a21 - a01*a22)*id;
    const float i02 = (a01*a12 - a02*a11)*id;
    const float i10 = (a12*a20 - a10*a22)*id;
    const float i11 = (a00*a22 - a02*a20)*id;
    const float i12 = (a02*a10 - a00*a12)*id;
    const float i20 = (a10*a21 - a11*a20)*id;
    const float i21 = (a01*a20 - a00*a21)*id;
    const float i22 = (a00*a11 - a01*a10)*id;

    // pts_p = (u*z, v*z, z)
    const float up = (float)col * z;
    const float vp = (float)row * z;
    const float pcx = i00*up + i01*vp + i02*z;
    const float pcy = i10*up + i11*vp + i12*z;
    const float pcz = i20*up + i21*vp + i22*z;

    // world coords = (E @ [pc,1])[:3]
    const float cwx = extr[0]*pcx + extr[1]*pcy + extr[2]*pcz  + extr[3];
    const float cwy = extr[4]*pcx + extr[5]*pcy + extr[6]*pcz  + extr[7];
    const float cwz = extr[8]*pcx + extr[9]*pcy + extr[10]*pcz + extr[11];

    const float ox = origin[0], oy = origin[1], oz = origin[2];
    const float res = resolution[0];

    // voxel coords
    const float cvx = (cwx - ox) / res;
    const float cvy = (cwy - oy) / res;
    const float cvz = (cwz - oz) / res;
    const float evx = (extr[3]  - ox) / res;
    const float evy = (extr[7]  - oy) / res;
    const float evz = (extr[11] - oz) / res;

    float dx = cvx - evx, dy = cvy - evy, dz = cvz - evz;
    const float nrm = sqrtf(dx*dx + dy*dy + dz*dz);
    const float dn  = fmaxf(nrm, 1e-12f);
    dx /= dn; dy /= dn; dz /= dn;

    const float offs = (float)(s - 4);   // offs in [-4,4]
    const float pt[3] = { cvx + offs*dx, cvy + offs*dy, cvz + offs*dz };

    // --- trilinear setup ---
    float alpha[3], nb[3], fidx[3];
    #pragma unroll
    for (int k = 0; k < 3; ++k) {
        const float f  = floorf(pt[k]);
        const float c  = f + 0.5f;
        const float df = c - pt[k];
        nb[k]    = (df > 0.0f) ? 1.0f : ((df < 0.0f) ? -1.0f : 0.0f);
        alpha[k] = fabsf(pt[k] - c);
        fidx[k]  = f;
    }

    float fv = 0.0f, fw = 0.0f;
    float indsbuf[24];
    float w8buf[8];

    #pragma unroll
    for (int c = 0; c < 8; ++c) {
        float wgt = 1.0f;
        bool valid = true;
        int ii[3];
        #pragma unroll
        for (int k = 0; k < 3; ++k) {
            const float bit = ((c >> (2 - k)) & 1) ? 1.0f : 0.0f;
            wgt *= (bit > 0.0f) ? alpha[k] : (1.0f - alpha[k]);
            const float fi = fidx[k] + bit * nb[k];
            valid = valid && (fi >= 0.0f) && (fi < (float)VDIM);
            const float fc = fminf(fmaxf(fi, 0.0f), (float)(VDIM - 1));
            ii[k] = (int)fc;
            indsbuf[c*3 + k] = (float)ii[k];
        }
        const int lin = (ii[0]*VDIM + ii[1])*VDIM + ii[2];
        const float v  = vol[lin];
        const float wv = wvol[lin];
        if (valid) { fv += v * wgt; fw += wv * wgt; }
        w8buf[c] = wgt;
    }

    // --- plain stores: L2 write-back merges covering writes into full lines ---
    out[OFF_FV + tid] = fv;
    out[OFF_FW + tid] = fw;
    out[OFF_RP + tid*3 + 0] = pt[0];
    out[OFF_RP + tid*3 + 1] = pt[1];
    out[OFF_RP + tid*3 + 2] = pt[2];

    f32x4* ip = reinterpret_cast<f32x4*>(out + OFF_I + tid*24);
    #pragma unroll
    for (int q = 0; q < 6; ++q) {
        f32x4 v4 = { indsbuf[q*4+0], indsbuf[q*4+1], indsbuf[q*4+2], indsbuf[q*4+3] };
        ip[q] = v4;
    }

    f32x4* wp = reinterpret_cast<f32x4*>(out + OFF_W8 + tid*8);
    f32x4 w0 = { w8buf[0], w8buf[1], w8buf[2], w8buf[3] };
    f32x4 w1 = { w8buf[4], w8buf[5], w8buf[6], w8buf[7] };
    wp[0] = w0;
    wp[1] = w1;

    if (s == 0) {
        out[OFF_D + p] = z;
        out[OFF_C + p*3 + 0] = cwx;
        out[OFF_C + p*3 + 1] = cwy;
        out[OFF_C + p*3 + 2] = cwz;
    }
}

extern "C" void kernel_launch(void* const* d_in, const int* in_sizes, int n_in,
                              void* d_out, int out_size, void* d_ws, size_t ws_size,
                              hipStream_t stream) {
    const float* depth      = (const float*)d_in[0];
    const float* extr       = (const float*)d_in[1];
    const float* intr       = (const float*)d_in[2];
    const float* vol        = (const float*)d_in[3];
    const float* wvol       = (const float*)d_in[4];
    const float* origin     = (const float*)d_in[5];
    const float* resolution = (const float*)d_in[6];
    float* out = (float*)d_out;

    extractor_kernel<<<NTILES, TILE*TILE*NS, 0, stream>>>(
        depth, extr, intr, vol, wvol, origin, resolution, out);
}

// Round 5
// 52.153 us; speedup vs baseline: 2.6558x; 1.3641x over previous
//
#include <hip/hip_runtime.h>

#define NPIX    76800      // 240*320
#define WIDTH   320
#define HEIGHT  240
#define NS      9
#define NTOT    (NPIX*NS)  // 691200
#define VDIM    320

// pixel tiling: 8x8 tiles in tile-scan order (locality for the gather footprint)
#define TILE    8
#define TILES_X 40

// launch: 256 threads/block over (pixel,sample) in tile order
#define BLOCK   256
#define NBLK    (NTOT / BLOCK)          // 2700
#define NXCD    8
#define SWZ_Q   (NBLK / NXCD)           // 337
#define SWZ_R   (NBLK % NXCD)           // 4

// output offsets (all float32 elements, concatenated in return order)
#define OFF_FV  0
#define OFF_FW  691200
#define OFF_RP  1382400
#define OFF_D   3456000
#define OFF_I   3532800
#define OFF_W8  20121600
#define OFF_C   25651200

typedef float f32x4 __attribute__((ext_vector_type(4)));

__global__ __launch_bounds__(BLOCK, 8) void extractor_kernel(
    const float* __restrict__ depth,
    const float* __restrict__ extr,      // 4x4 row-major
    const float* __restrict__ intr,      // 3x3 row-major
    const float* __restrict__ vol,       // 320^3
    const float* __restrict__ wvol,      // 320^3
    const float* __restrict__ origin,    // 3
    const float* __restrict__ resolution,// 1
    float* __restrict__ out)
{
    // ---- bijective chunked XCD swizzle (2700 = 8*337 + 4) ----
    const int bid  = blockIdx.x;
    const int xcd  = bid & (NXCD - 1);
    const int base = bid >> 3;
    const int swz  = (xcd < SWZ_R ? xcd * (SWZ_Q + 1)
                                  : SWZ_R * (SWZ_Q + 1) + (xcd - SWZ_R) * SWZ_Q) + base;

    const int g = swz * BLOCK + threadIdx.x;   // global (pixel,sample) work index
    const int q = g / 9;                       // pixel in tile-scan order
    const int s = g - q * 9;                   // sample 0..8

    const int tileIdx  = q >> 6;               // 64 pixels per tile
    const int lp       = q & 63;
    const int tile_row = tileIdx / TILES_X;
    const int tile_col = tileIdx - tile_row * TILES_X;
    const int row = tile_row * TILE + (lp >> 3);   // v
    const int col = tile_col * TILE + (lp & 7);    // u
    const int p   = row * WIDTH + col;
    const int tid = p * NS + s;                // output index

    const float z = depth[p];

    // --- 3x3 inverse of intrinsics (adjugate; uniform values) ---
    const float a00=intr[0], a01=intr[1], a02=intr[2];
    const float a10=intr[3], a11=intr[4], a12=intr[5];
    const float a20=intr[6], a21=intr[7], a22=intr[8];
    const float det = a00*(a11*a22 - a12*a21)
                    - a01*(a10*a22 - a12*a20)
                    + a02*(a10*a21 - a11*a20);
    const float id = 1.0f / det;
    const float i00 = (a11*a22 - a12*a21)*id;
    const float i01 = (a02*a21 - a01*a22)*id;
    const float i02 = (a01*a12 - a02*a11)*id;
    const float i10 = (a12*a20 - a10*a22)*id;
    const float i11 = (a00*a22 - a02*a20)*id;
    const float i12 = (a02*a10 - a00*a12)*id;
    const float i20 = (a10*a21 - a11*a20)*id;
    const float i21 = (a01*a20 - a00*a21)*id;
    const float i22 = (a00*a11 - a01*a10)*id;

    // pts_p = (u*z, v*z, z)
    const float up = (float)col * z;
    const float vp = (float)row * z;
    const float pcx = i00*up + i01*vp + i02*z;
    const float pcy = i10*up + i11*vp + i12*z;
    const float pcz = i20*up + i21*vp + i22*z;

    // world coords = (E @ [pc,1])[:3]
    const float cwx = extr[0]*pcx + extr[1]*pcy + extr[2]*pcz  + extr[3];
    const float cwy = extr[4]*pcx + extr[5]*pcy + extr[6]*pcz  + extr[7];
    const float cwz = extr[8]*pcx + extr[9]*pcy + extr[10]*pcz + extr[11];

    const float ox = origin[0], oy = origin[1], oz = origin[2];
    const float res = resolution[0];

    // voxel coords
    const float cvx = (cwx - ox) / res;
    const float cvy = (cwy - oy) / res;
    const float cvz = (cwz - oz) / res;
    const float evx = (extr[3]  - ox) / res;
    const float evy = (extr[7]  - oy) / res;
    const float evz = (extr[11] - oz) / res;

    float dx = cvx - evx, dy = cvy - evy, dz = cvz - evz;
    const float nrm = sqrtf(dx*dx + dy*dy + dz*dz);
    const float dn  = fmaxf(nrm, 1e-12f);
    dx /= dn; dy /= dn; dz /= dn;

    const float offs = (float)(s - 4);   // offs in [-4,4]
    const float pt[3] = { cvx + offs*dx, cvy + offs*dy, cvz + offs*dz };

    // --- trilinear setup ---
    float alpha[3], nb[3], fidx[3];
    #pragma unroll
    for (int k = 0; k < 3; ++k) {
        const float f  = floorf(pt[k]);
        const float c  = f + 0.5f;
        const float df = c - pt[k];
        nb[k]    = (df > 0.0f) ? 1.0f : ((df < 0.0f) ? -1.0f : 0.0f);
        alpha[k] = fabsf(pt[k] - c);
        fidx[k]  = f;
    }

    // phase 1: all addresses + weights + validity (no loads yet)
    int   lin[8];
    float wgt8[8];
    bool  valid8[8];
    float indsbuf[24];
    #pragma unroll
    for (int c = 0; c < 8; ++c) {
        float wgt = 1.0f;
        bool valid = true;
        int ii[3];
        #pragma unroll
        for (int k = 0; k < 3; ++k) {
            const float bit = ((c >> (2 - k)) & 1) ? 1.0f : 0.0f;
            wgt *= (bit > 0.0f) ? alpha[k] : (1.0f - alpha[k]);
            const float fi = fidx[k] + bit * nb[k];
            valid = valid && (fi >= 0.0f) && (fi < (float)VDIM);
            const float fc = fminf(fmaxf(fi, 0.0f), (float)(VDIM - 1));
            ii[k] = (int)fc;
            indsbuf[c*3 + k] = (float)ii[k];
        }
        lin[c]    = (ii[0]*VDIM + ii[1])*VDIM + ii[2];
        wgt8[c]   = wgt;
        valid8[c] = valid;
    }

    // phase 2: issue all 16 gathers back-to-back (max memory-level parallelism)
    float v8[8], wv8[8];
    #pragma unroll
    for (int c = 0; c < 8; ++c) v8[c]  = vol[lin[c]];
    #pragma unroll
    for (int c = 0; c < 8; ++c) wv8[c] = wvol[lin[c]];

    // phase 3: stores that do NOT depend on the gathers
    out[OFF_RP + tid*3 + 0] = pt[0];
    out[OFF_RP + tid*3 + 1] = pt[1];
    out[OFF_RP + tid*3 + 2] = pt[2];

    f32x4* ip = reinterpret_cast<f32x4*>(out + OFF_I + tid*24);
    #pragma unroll
    for (int qd = 0; qd < 6; ++qd) {
        f32x4 v4 = { indsbuf[qd*4+0], indsbuf[qd*4+1], indsbuf[qd*4+2], indsbuf[qd*4+3] };
        ip[qd] = v4;
    }

    f32x4* wp = reinterpret_cast<f32x4*>(out + OFF_W8 + tid*8);
    f32x4 w0 = { wgt8[0], wgt8[1], wgt8[2], wgt8[3] };
    f32x4 w1 = { wgt8[4], wgt8[5], wgt8[6], wgt8[7] };
    wp[0] = w0;
    wp[1] = w1;

    if (s == 0) {
        out[OFF_D + p] = z;
        out[OFF_C + p*3 + 0] = cwx;
        out[OFF_C + p*3 + 1] = cwy;
        out[OFF_C + p*3 + 2] = cwz;
    }

    // phase 4: consume gathers
    float fv = 0.0f, fw = 0.0f;
    #pragma unroll
    for (int c = 0; c < 8; ++c) {
        if (valid8[c]) { fv += v8[c] * wgt8[c]; fw += wv8[c] * wgt8[c]; }
    }
    out[OFF_FV + tid] = fv;
    out[OFF_FW + tid] = fw;
}

extern "C" void kernel_launch(void* const* d_in, const int* in_sizes, int n_in,
                              void* d_out, int out_size, void* d_ws, size_t ws_size,
                              hipStream_t stream) {
    const float* depth      = (const float*)d_in[0];
    const float* extr       = (const float*)d_in[1];
    const float* intr       = (const float*)d_in[2];
    const float* vol        = (const float*)d_in[3];
    const float* wvol       = (const float*)d_in[4];
    const float* origin     = (const float*)d_in[5];
    const float* resolution = (const float*)d_in[6];
    float* out = (float*)d_out;

    extractor_kernel<<<NBLK, BLOCK, 0, stream>>>(
        depth, extr, intr, vol, wvol, origin, resolution, out);
}

// Round 6
// 45.869 us; speedup vs baseline: 3.0197x; 1.1370x over previous
//
#include <hip/hip_runtime.h>

#define NPIX    76800      // 240*320
#define WIDTH   320
#define NS      9
#define NTOT    (NPIX*NS)  // 691200
#define VDIM    320

// launch: identity mapping (tid = g), 256 threads/block, 2700 blocks
#define BLOCK   256
#define NBLK    (NTOT / BLOCK)          // 2700
#define NXCD    8
#define SWZ_Q   (NBLK / NXCD)           // 337
#define SWZ_R   (NBLK % NXCD)           // 4

// output offsets (all float32 elements, concatenated in return order)
#define OFF_FV  0
#define OFF_FW  691200
#define OFF_RP  1382400
#define OFF_D   3456000
#define OFF_I   3532800
#define OFF_W8  20121600
#define OFF_C   25651200

typedef float f32x4 __attribute__((ext_vector_type(4)));

__global__ __launch_bounds__(BLOCK, 6) void extractor_kernel(
    const float* __restrict__ depth,
    const float* __restrict__ extr,      // 4x4 row-major
    const float* __restrict__ intr,      // 3x3 row-major
    const float* __restrict__ vol,       // 320^3
    const float* __restrict__ wvol,      // 320^3
    const float* __restrict__ origin,    // 3
    const float* __restrict__ resolution,// 1
    float* __restrict__ out)
{
    __shared__ f32x4 lds4[BLOCK * 6];    // 24 KiB: staging for inds, reused for w8

    // ---- bijective chunked XCD swizzle (2700 = 8*337 + 4) ----
    const int bid  = blockIdx.x;
    const int xcd  = bid & (NXCD - 1);
    const int base = bid >> 3;
    const int swz  = (xcd < SWZ_R ? xcd * (SWZ_Q + 1)
                                  : SWZ_R * (SWZ_Q + 1) + (xcd - SWZ_R) * SWZ_Q) + base;

    const int t   = threadIdx.x;
    const int gB  = swz * BLOCK;         // block's base output index
    const int tid = gB + t;              // identity: output index == work index
    const int p   = tid / 9;             // pixel (row-major)
    const int s   = tid - p * 9;         // sample 0..8

    const int row = p / WIDTH;           // v
    const int col = p - row * WIDTH;     // u

    const float z = depth[p];

    // --- 3x3 inverse of intrinsics (adjugate; uniform values) ---
    const float a00=intr[0], a01=intr[1], a02=intr[2];
    const float a10=intr[3], a11=intr[4], a12=intr[5];
    const float a20=intr[6], a21=intr[7], a22=intr[8];
    const float det = a00*(a11*a22 - a12*a21)
                    - a01*(a10*a22 - a12*a20)
                    + a02*(a10*a21 - a11*a20);
    const float id = 1.0f / det;
    const float i00 = (a11*a22 - a12*a21)*id;
    const float i01 = (a02*a21 - a01*a22)*id;
    const float i02 = (a01*a12 - a02*a11)*id;
    const float i10 = (a12*a20 - a10*a22)*id;
    const float i11 = (a00*a22 - a02*a20)*id;
    const float i12 = (a02*a10 - a00*a12)*id;
    const float i20 = (a10*a21 - a11*a20)*id;
    const float i21 = (a01*a20 - a00*a21)*id;
    const float i22 = (a00*a11 - a01*a10)*id;

    // pts_p = (u*z, v*z, z)
    const float up = (float)col * z;
    const float vp = (float)row * z;
    const float pcx = i00*up + i01*vp + i02*z;
    const float pcy = i10*up + i11*vp + i12*z;
    const float pcz = i20*up + i21*vp + i22*z;

    // world coords = (E @ [pc,1])[:3]
    const float cwx = extr[0]*pcx + extr[1]*pcy + extr[2]*pcz  + extr[3];
    const float cwy = extr[4]*pcx + extr[5]*pcy + extr[6]*pcz  + extr[7];
    const float cwz = extr[8]*pcx + extr[9]*pcy + extr[10]*pcz + extr[11];

    const float ox = origin[0], oy = origin[1], oz = origin[2];
    const float res = resolution[0];

    // voxel coords
    const float cvx = (cwx - ox) / res;
    const float cvy = (cwy - oy) / res;
    const float cvz = (cwz - oz) / res;
    const float evx = (extr[3]  - ox) / res;
    const float evy = (extr[7]  - oy) / res;
    const float evz = (extr[11] - oz) / res;

    float dx = cvx - evx, dy = cvy - evy, dz = cvz - evz;
    const float nrm = sqrtf(dx*dx + dy*dy + dz*dz);
    const float dn  = fmaxf(nrm, 1e-12f);
    dx /= dn; dy /= dn; dz /= dn;

    const float offs = (float)(s - 4);   // offs in [-4,4]
    const float pt[3] = { cvx + offs*dx, cvy + offs*dy, cvz + offs*dz };

    // --- trilinear setup ---
    float alpha[3], nb[3], fidx[3];
    #pragma unroll
    for (int k = 0; k < 3; ++k) {
        const float f  = floorf(pt[k]);
        const float c  = f + 0.5f;
        const float df = c - pt[k];
        nb[k]    = (df > 0.0f) ? 1.0f : ((df < 0.0f) ? -1.0f : 0.0f);
        alpha[k] = fabsf(pt[k] - c);
        fidx[k]  = f;
    }

    // phase 1: all addresses + weights + validity (no loads yet)
    int   lin[8];
    float wgt8[8];
    bool  valid8[8];
    float indsbuf[24];
    #pragma unroll
    for (int c = 0; c < 8; ++c) {
        float wgt = 1.0f;
        bool valid = true;
        int ii[3];
        #pragma unroll
        for (int k = 0; k < 3; ++k) {
            const float bit = ((c >> (2 - k)) & 1) ? 1.0f : 0.0f;
            wgt *= (bit > 0.0f) ? alpha[k] : (1.0f - alpha[k]);
            const float fi = fidx[k] + bit * nb[k];
            valid = valid && (fi >= 0.0f) && (fi < (float)VDIM);
            const float fc = fminf(fmaxf(fi, 0.0f), (float)(VDIM - 1));
            ii[k] = (int)fc;
            indsbuf[c*3 + k] = (float)ii[k];
        }
        lin[c]    = (ii[0]*VDIM + ii[1])*VDIM + ii[2];
        wgt8[c]   = wgt;
        valid8[c] = valid;
    }

    // phase 2: issue all 16 gathers back-to-back (max memory-level parallelism)
    float v8[8], wv8[8];
    #pragma unroll
    for (int c = 0; c < 8; ++c) v8[c]  = vol[lin[c]];
    #pragma unroll
    for (int c = 0; c < 8; ++c) wv8[c] = wvol[lin[c]];

    // phase 3: gather-independent direct stores (already coalesced under identity map)
    out[OFF_RP + tid*3 + 0] = pt[0];
    out[OFF_RP + tid*3 + 1] = pt[1];
    out[OFF_RP + tid*3 + 2] = pt[2];
    if (s == 0) {
        out[OFF_D + p] = z;
        out[OFF_C + p*3 + 0] = cwx;
        out[OFF_C + p*3 + 1] = cwy;
        out[OFF_C + p*3 + 2] = cwz;
    }

    // phase 4: consume gathers
    float fv = 0.0f, fw = 0.0f;
    #pragma unroll
    for (int c = 0; c < 8; ++c) {
        if (valid8[c]) { fv += v8[c] * wgt8[c]; fw += wv8[c] * wgt8[c]; }
    }
    out[OFF_FV + tid] = fv;
    out[OFF_FW + tid] = fw;

    // phase 5: inds via LDS transpose -> fully coalesced 24 KB contiguous write
    // LDS layout = linear image of the block's inds region (float4 slot l*6+c)
    #pragma unroll
    for (int c = 0; c < 6; ++c) {
        f32x4 v4 = { indsbuf[c*4+0], indsbuf[c*4+1], indsbuf[c*4+2], indsbuf[c*4+3] };
        lds4[t*6 + c] = v4;
    }
    __syncthreads();
    f32x4* outI = reinterpret_cast<f32x4*>(out + OFF_I) + gB*6;
    #pragma unroll
    for (int it = 0; it < 6; ++it)
        outI[it*BLOCK + t] = lds4[it*BLOCK + t];
    __syncthreads();

    // phase 6: w8 via LDS (reuse region) -> coalesced 8 KB contiguous write
    f32x4 w0 = { wgt8[0], wgt8[1], wgt8[2], wgt8[3] };
    f32x4 w1 = { wgt8[4], wgt8[5], wgt8[6], wgt8[7] };
    lds4[t*2 + 0] = w0;
    lds4[t*2 + 1] = w1;
    __syncthreads();
    f32x4* outW = reinterpret_cast<f32x4*>(out + OFF_W8) + gB*2;
    outW[t]         = lds4[t];
    outW[BLOCK + t] = lds4[BLOCK + t];
}

extern "C" void kernel_launch(void* const* d_in, const int* in_sizes, int n_in,
                              void* d_out, int out_size, void* d_ws, size_t ws_size,
                              hipStream_t stream) {
    const float* depth      = (const float*)d_in[0];
    const float* extr       = (const float*)d_in[1];
    const float* intr       = (const float*)d_in[2];
    const float* vol        = (const float*)d_in[3];
    const float* wvol       = (const float*)d_in[4];
    const float* origin     = (const float*)d_in[5];
    const float* resolution = (const float*)d_in[6];
    float* out = (float*)d_out;

    extractor_kernel<<<NBLK, BLOCK, 0, stream>>>(
        depth, extr, intr, vol, wvol, origin, resolution, out);
}